// Round 15
// baseline (249.323 us; speedup 1.0000x reference)
//
#include <hip/hip_runtime.h>
#include <math.h>

#define EMBED 1024
#define HEADS 16
#define HD 64
#define BATCH 4
#define TSEQ 4096
#define BH (BATCH * HEADS)
#define MROWS (BATCH * TSEQ)   // 16384

typedef _Float16 f16;
typedef __attribute__((ext_vector_type(4))) _Float16 f16x4;
typedef __attribute__((ext_vector_type(8))) _Float16 f16x8;
typedef __attribute__((ext_vector_type(4))) float f32x4;

#define GLOBAL_AS __attribute__((address_space(1)))
#define LDS_AS __attribute__((address_space(3)))

__device__ __forceinline__ float elu1(float v) {
    return v > 0.f ? v + 1.f : __expf(v);
}

// XOR-swizzled element offset in a [rows][cols] f16 tile; 16B granules.
__device__ __forceinline__ int swzc(int row, int col, int cols) {
    int g = (col >> 3) ^ (row & 7);
    return row * cols + (g << 3) + (col & 7);
}

__device__ __forceinline__ f16x8 fragld(const f16* t, int row, int k, int cols) {
    return *(const f16x8*)&t[swzc(row, k, cols)];
}

__device__ __forceinline__ f32x4 mfma16(f16x8 a, f16x8 b, f32x4 c) {
    return __builtin_amdgcn_mfma_f32_16x16x32_f16(a, b, c, 0, 0, 0);
}

// async global->LDS, 16B per lane. lds dest must be wave-uniform base.
__device__ __forceinline__ void gld_lds16(const f16* g, f16* l) {
    __builtin_amdgcn_global_load_lds((const GLOBAL_AS void*)g, (LDS_AS void*)l, 16, 0, 0);
}

// ---------------------------------------------------------------------------
// prep: blocks [0,16384): x fp32 -> f16.  blocks [16384,20480): pack weights
// f16 + biases + zero kv/ks accumulators.
// ---------------------------------------------------------------------------
__global__ __launch_bounds__(256) void prep(
    const float* __restrict__ x, f16* __restrict__ xh,
    const float* __restrict__ Wq, const float* __restrict__ Wk,
    const float* __restrict__ Wv, const float* __restrict__ Wc,
    const float* __restrict__ bq, const float* __restrict__ bk,
    const float* __restrict__ bv, const float* __restrict__ bc,
    f16* __restrict__ Wall, float* __restrict__ ball, float* __restrict__ kvz)
{
    int bid = blockIdx.x;
    if (bid < 16384) {
        size_t i4 = (size_t)bid * 256 + threadIdx.x;
        float4 f = *(const float4*)&x[i4 * 4];
        f16x4 h = {(f16)f.x, (f16)f.y, (f16)f.z, (f16)f.w};
        *(f16x4*)&xh[i4 * 4] = h;
    } else {
        int i4 = (bid - 16384) * 256 + threadIdx.x;    // < 1048576
        int cls = i4 >> 18;
        const float* W = cls == 0 ? Wq : cls == 1 ? Wk : cls == 2 ? Wv : Wc;
        int off = (i4 & 0x3FFFF) * 4;
        float4 f = *(const float4*)&W[off];
        f16x4 h = {(f16)f.x, (f16)f.y, (f16)f.z, (f16)f.w};
        *(f16x4*)&Wall[(size_t)i4 * 4] = h;
        if (i4 < 4096) {
            int c2 = i4 >> 10;
            const float* bb = c2 == 0 ? bq : c2 == 1 ? bk : c2 == 2 ? bv : bc;
            ball[i4] = bb[i4 & 1023];
        }
        if (i4 < 66560) {   // (64*64*64 + 64*64)/4 floats of kv+ks
            *(float4*)&kvz[i4 * 4] = (float4){0.f, 0.f, 0.f, 0.f};
        }
    }
}

// ---------------------------------------------------------------------------
// gemm_kv: grid (32 m-chunks, 16 heads); each block loops over 4 m-tiles of
// one batch. Per tile: C[128t x 128c] = xh @ [Wk_h;Wv_h]^T,
// k=elu(C[:,0:64]+bk), v=C[:,64:128]+bv -> LDS transposed ->
// kvacc += v^T k (reg, MFMA), ksacc += sum_t k. Single atomic flush per
// block. (r14-verified: 92 us, MfmaUtil 33)
// ---------------------------------------------------------------------------
__global__ __launch_bounds__(256) void gemm_kv(
    const f16* __restrict__ xh, const f16* __restrict__ Wall,
    const float* __restrict__ ball,
    float* __restrict__ kvg, float* __restrict__ ksg)
{
    __shared__ __align__(16) f16 smem[2 * 128 * 64];   // As | Bs (32KB)
    f16* As = smem;
    f16* Bs = smem + 128 * 64;

    const int tid = threadIdx.x, lane = tid & 63, w = tid >> 6;
    const int wr = w >> 1, wc4 = w & 1, l15 = lane & 15, l4 = lane >> 4;

    const int h = blockIdx.y;

    const int gcol = ((lane & 7) ^ (lane >> 3)) << 3;
    const int rsub = lane >> 3;

    const int wrow = w * 32 + rsub;       // 0..127
    const int brow_idx = (wrow < 64) ? (1024 + h * 64 + wrow)
                                     : (2048 + h * 64 + (wrow - 64));
    const size_t brow = (size_t)brow_idx * EMBED + gcol;
    const float* biasp = ball + (wc4 ? 2048 : 1024) + h * 64;

    f32x4 kvacc[4];
    #pragma unroll
    for (int j = 0; j < 4; ++j) kvacc[j] = (f32x4){0.f, 0.f, 0.f, 0.f};
    float ksacc = 0.f;

    for (int mi = 0; mi < 4; ++mi) {
        const int m0 = (blockIdx.x * 4 + mi) * 128;
        const size_t arow = (size_t)(m0 + w * 32 + rsub) * EMBED + gcol;

        f32x4 acc[4][4];
        #pragma unroll
        for (int i = 0; i < 4; ++i)
            #pragma unroll
            for (int j = 0; j < 4; ++j) acc[i][j] = (f32x4){0.f, 0.f, 0.f, 0.f};

        for (int k0 = 0; k0 < EMBED; k0 += 64) {
            #pragma unroll
            for (int c = 0; c < 4; ++c) {
                gld_lds16(&xh[arow + (size_t)c * 8 * EMBED + k0], &As[(w * 4 + c) * 512]);
                gld_lds16(&Wall[brow + (size_t)c * 8 * EMBED + k0], &Bs[(w * 4 + c) * 512]);
            }
            __syncthreads();
            #pragma unroll
            for (int kk = 0; kk < 64; kk += 32) {
                f16x8 af[4], bf[4];
                #pragma unroll
                for (int i = 0; i < 4; ++i)
                    af[i] = fragld(As, wr * 64 + i * 16 + l15, kk + l4 * 8, 64);
                #pragma unroll
                for (int j = 0; j < 4; ++j)
                    bf[j] = fragld(Bs, wc4 * 64 + j * 16 + l15, kk + l4 * 8, 64);
                #pragma unroll
                for (int i = 0; i < 4; ++i)
                    #pragma unroll
                    for (int j = 0; j < 4; ++j)
                        acc[i][j] = mfma16(af[i], bf[j], acc[i][j]);
            }
            __syncthreads();
        }

        // kv epilogue: acc -> kt/vt LDS [64 d][128 t] (transposed, swizzled)
        f16* kt = As;
        f16* vt = Bs;
        #pragma unroll
        for (int j = 0; j < 4; ++j) {
            int d = j * 16 + l15;
            float bj = biasp[d];
            f16* dst = wc4 ? vt : kt;
            #pragma unroll
            for (int i = 0; i < 4; ++i) {
                int t0 = wr * 64 + i * 16 + l4 * 4;
                f16x4 hv;
                #pragma unroll
                for (int r = 0; r < 4; ++r) {
                    float vv = acc[i][j][r] + bj;
                    if (!wc4) vv = elu1(vv);
                    hv[r] = (f16)vv;
                }
                *(f16x4*)&dst[swzc(d, t0, 128)] = hv;
            }
        }
        __syncthreads();

        // kvacc[e][d] += sum_t v[t,e] k[t,d]; wave w owns e range [16w,16w+16)
        #pragma unroll
        for (int tc = 0; tc < 4; ++tc) {
            f16x8 a = fragld(vt, 16 * w + l15, tc * 32 + l4 * 8, 128);
            #pragma unroll
            for (int j = 0; j < 4; ++j) {
                f16x8 bfr = fragld(kt, j * 16 + l15, tc * 32 + l4 * 8, 128);
                kvacc[j] = mfma16(a, bfr, kvacc[j]);
            }
        }
        {
            int d = tid & 63, q4 = tid >> 6;
            #pragma unroll
            for (int t8 = 0; t8 < 32; t8 += 8) {
                f16x8 k8 = fragld(kt, d, q4 * 32 + t8, 128);
                #pragma unroll
                for (int e = 0; e < 8; ++e) ksacc += (float)k8[e];
            }
        }
        __syncthreads();   // kt/vt reads done before next chunk re-stages As/Bs
    }

    const int bh = (blockIdx.x >> 3) * HEADS + h;   // 8 m-chunks per batch
    #pragma unroll
    for (int j = 0; j < 4; ++j)
        #pragma unroll
        for (int r = 0; r < 4; ++r)
            atomicAdd(&kvg[(size_t)bh * 4096 +
                           (size_t)(16 * w + l4 * 4 + r) * HD + j * 16 + l15],
                      kvacc[j][r]);
    atomicAdd(&ksg[bh * HD + (tid & 63)], ksacc);
}

// ---------------------------------------------------------------------------
// gemm_qy: grid (32 m-chunks, 8 q-classes); block loops 4 m-tiles of one
// batch. Per tile: q for heads 2ny,2ny+1, in-block z + y = (q @ kv)*z,
// coalesced y store. kvs/kss staged ONCE per block (bh0 block-constant).
// ---------------------------------------------------------------------------
__global__ __launch_bounds__(256) void gemm_qy(
    const f16* __restrict__ xh, const f16* __restrict__ Wall,
    const float* __restrict__ ball,
    const float* __restrict__ kvg, const float* __restrict__ ksg,
    f16* __restrict__ y)
{
    __shared__ __align__(16) f16 smem[2 * 128 * 64];   // As|Bs -> qtile -> ytile
    __shared__ __align__(16) f16 kvs[2][64 * 64];      // per-head kv (f16, swz)
    __shared__ float kss[2][64];
    __shared__ float zs[128][2];
    f16* As = smem;
    f16* Bs = smem + 128 * 64;

    const int tid = threadIdx.x, lane = tid & 63, w = tid >> 6;
    const int wr = w >> 1, wc4 = w & 1, l15 = lane & 15, l4 = lane >> 4;

    const int ny = blockIdx.y;            // 0..7
    const int n0 = ny * 128;
    const int batch = blockIdx.x >> 3;    // 8 m-chunks per batch
    const int bh0 = batch * HEADS + 2 * ny;

    const int gcol = ((lane & 7) ^ (lane >> 3)) << 3;
    const int rsub = lane >> 3;
    const size_t brow = (size_t)(n0 + w * 32 + rsub) * EMBED + gcol;

    // stage kv for both heads (fp32 -> f16, swizzled) + ksum — once per block
    #pragma unroll
    for (int c = 0; c < 8; ++c) {
        int idx = tid + c * 256;          // 0..2047
        int hh = idx >> 10;
        int rem = idx & 1023;
        int e = rem >> 4, d4 = (rem & 15) << 2;
        float4 f = *(const float4*)&kvg[(size_t)(bh0 + hh) * 4096 + e * 64 + d4];
        f16x4 hv = {(f16)f.x, (f16)f.y, (f16)f.z, (f16)f.w};
        *(f16x4*)&kvs[hh][swzc(e, d4, 64)] = hv;
    }
    if (tid < 128) kss[tid >> 6][tid & 63] = ksg[(bh0 + (tid >> 6)) * HD + (tid & 63)];

    const int hh = w >> 1;                // y-MFMA wave mapping
    const int eh = (w & 1) * 32;

    for (int mi = 0; mi < 4; ++mi) {
        const int m0 = (blockIdx.x * 4 + mi) * 128;
        const size_t arow = (size_t)(m0 + w * 32 + rsub) * EMBED + gcol;

        f32x4 acc[4][4];
        #pragma unroll
        for (int i = 0; i < 4; ++i)
            #pragma unroll
            for (int j = 0; j < 4; ++j) acc[i][j] = (f32x4){0.f, 0.f, 0.f, 0.f};

        for (int k0 = 0; k0 < EMBED; k0 += 64) {
            #pragma unroll
            for (int c = 0; c < 4; ++c) {
                gld_lds16(&xh[arow + (size_t)c * 8 * EMBED + k0], &As[(w * 4 + c) * 512]);
                gld_lds16(&Wall[brow + (size_t)c * 8 * EMBED + k0], &Bs[(w * 4 + c) * 512]);
            }
            __syncthreads();
            #pragma unroll
            for (int kk = 0; kk < 64; kk += 32) {
                f16x8 af[4], bf[4];
                #pragma unroll
                for (int i = 0; i < 4; ++i)
                    af[i] = fragld(As, wr * 64 + i * 16 + l15, kk + l4 * 8, 64);
                #pragma unroll
                for (int j = 0; j < 4; ++j)
                    bf[j] = fragld(Bs, wc4 * 64 + j * 16 + l15, kk + l4 * 8, 64);
                #pragma unroll
                for (int i = 0; i < 4; ++i)
                    #pragma unroll
                    for (int j = 0; j < 4; ++j)
                        acc[i][j] = mfma16(af[i], bf[j], acc[i][j]);
            }
            __syncthreads();
        }

        // q epilogue -> qtile smem [128 t][128 c] swizzled
        #pragma unroll
        for (int j = 0; j < 4; ++j) {
            int c = wc4 * 64 + j * 16 + l15;
            float bj = ball[n0 + c];
            #pragma unroll
            for (int i = 0; i < 4; ++i) {
                #pragma unroll
                for (int r = 0; r < 4; ++r) {
                    int t = wr * 64 + i * 16 + l4 * 4 + r;
                    smem[swzc(t, c, 128)] = (f16)elu1(acc[i][j][r] + bj);
                }
            }
        }
        __syncthreads();

        // z[t][hh2] = 1/(q[t, hh2-head] . ksum + 1e-6); one thread per (t,hh2)
        {
            int t = tid >> 1, hh2 = tid & 1;
            float s = 0.f;
            #pragma unroll
            for (int d8 = 0; d8 < 64; d8 += 8) {
                f16x8 qv = fragld(smem, t, hh2 * 64 + d8, 128);
                #pragma unroll
                for (int e = 0; e < 8; ++e) s += (float)qv[e] * kss[hh2][d8 + e];
            }
            zs[t][hh2] = 1.f / (s + 1e-6f);
        }

        // y^T[e][t] per head: wave w -> head hh=w>>1, e-half (w&1)*32
        f32x4 yacc[2][8];
        #pragma unroll
        for (int et = 0; et < 2; ++et)
            #pragma unroll
            for (int jn = 0; jn < 8; ++jn) yacc[et][jn] = (f32x4){0.f, 0.f, 0.f, 0.f};
        #pragma unroll
        for (int kk = 0; kk < 64; kk += 32) {
            f16x8 a0 = fragld(kvs[hh], eh + l15, kk + l4 * 8, 64);
            f16x8 a1 = fragld(kvs[hh], eh + 16 + l15, kk + l4 * 8, 64);
            #pragma unroll
            for (int jn = 0; jn < 8; ++jn) {
                f16x8 bq8 = fragld(smem, jn * 16 + l15, hh * 64 + kk + l4 * 8, 128);
                yacc[0][jn] = mfma16(a0, bq8, yacc[0][jn]);
                yacc[1][jn] = mfma16(a1, bq8, yacc[1][jn]);
            }
        }
        __syncthreads();   // qtile reads done; zs visible

        // scale by z, write ytile into smem [128 t][128 c] swizzled
        #pragma unroll
        for (int et = 0; et < 2; ++et) {
            #pragma unroll
            for (int jn = 0; jn < 8; ++jn) {
                int t = jn * 16 + l15;
                float z = zs[t][hh];
                int c0 = hh * 64 + eh + et * 16 + l4 * 4;
                f16x4 hv;
                #pragma unroll
                for (int r = 0; r < 4; ++r) hv[r] = (f16)(yacc[et][jn][r] * z);
                *(f16x4*)&smem[swzc(t, c0, 128)] = hv;
            }
        }
        __syncthreads();

        // coalesced y store
        #pragma unroll
        for (int p = 0; p < 8; ++p) {
            int idx = tid + p * 256;
            int row = idx >> 4, g8 = (idx & 15) << 3;
            f16x8 v = *(const f16x8*)&smem[swzc(row, g8, 128)];
            *(f16x8*)&y[(size_t)(m0 + row) * EMBED + n0 + g8] = v;
        }
        __syncthreads();   // smem reads done before next chunk re-stages As/Bs
    }
}

// ---------------------------------------------------------------------------
// gemm_out: grid (32 m-chunks, 8 n-tiles); block loops 4 m-tiles.
// out[M,1024] = y @ Wc^T + bc (Wc = Wall rows 3072..4095), fp32 nontemporal.
// ---------------------------------------------------------------------------
__global__ __launch_bounds__(256) void gemm_out(
    const f16* __restrict__ y, const f16* __restrict__ Wall,
    const float* __restrict__ ball, float* __restrict__ out)
{
    __shared__ __align__(16) f16 As[128 * 64];
    __shared__ __align__(16) f16 Bs[128 * 64];

    const int tid = threadIdx.x, lane = tid & 63, w = tid >> 6;
    const int wr = w >> 1, wc4 = w & 1, l15 = lane & 15, l4 = lane >> 4;
    const int n0 = blockIdx.y * 128;

    const int gcol = ((lane & 7) ^ (lane >> 3)) << 3;
    const int rsub = lane >> 3;
    const size_t brow = (size_t)(3072 + n0 + w * 32 + rsub) * EMBED + gcol;

    for (int mi = 0; mi < 4; ++mi) {
        const int m0 = (blockIdx.x * 4 + mi) * 128;
        const size_t arow = (size_t)(m0 + w * 32 + rsub) * EMBED + gcol;

        f32x4 acc[4][4];
        #pragma unroll
        for (int i = 0; i < 4; ++i)
            #pragma unroll
            for (int j = 0; j < 4; ++j) acc[i][j] = (f32x4){0.f, 0.f, 0.f, 0.f};

        for (int k0 = 0; k0 < EMBED; k0 += 64) {
            #pragma unroll
            for (int c = 0; c < 4; ++c) {
                gld_lds16(&y[arow + (size_t)c * 8 * EMBED + k0], &As[(w * 4 + c) * 512]);
                gld_lds16(&Wall[brow + (size_t)c * 8 * EMBED + k0], &Bs[(w * 4 + c) * 512]);
            }
            __syncthreads();
            #pragma unroll
            for (int kk = 0; kk < 64; kk += 32) {
                f16x8 af[4], bf[4];
                #pragma unroll
                for (int i = 0; i < 4; ++i)
                    af[i] = fragld(As, wr * 64 + i * 16 + l15, kk + l4 * 8, 64);
                #pragma unroll
                for (int j = 0; j < 4; ++j)
                    bf[j] = fragld(Bs, wc4 * 64 + j * 16 + l15, kk + l4 * 8, 64);
                #pragma unroll
                for (int i = 0; i < 4; ++i)
                    #pragma unroll
                    for (int j = 0; j < 4; ++j)
                        acc[i][j] = mfma16(af[i], bf[j], acc[i][j]);
            }
            __syncthreads();
        }

        #pragma unroll
        for (int j = 0; j < 4; ++j) {
            int n = n0 + wc4 * 64 + j * 16 + l15;
            float bj = ball[3072 + n];
            #pragma unroll
            for (int i = 0; i < 4; ++i) {
                #pragma unroll
                for (int r = 0; r < 4; ++r) {
                    int m = m0 + wr * 64 + i * 16 + l4 * 4 + r;
                    __builtin_nontemporal_store(acc[i][j][r] + bj,
                                                &out[(size_t)m * EMBED + n]);
                }
            }
        }
    }
}

// ---------------------------------------------------------------------------
extern "C" void kernel_launch(void* const* d_in, const int* in_sizes, int n_in,
                              void* d_out, int out_size, void* d_ws, size_t ws_size,
                              hipStream_t stream) {
    (void)in_sizes; (void)n_in; (void)out_size; (void)ws_size;
    const float* x  = (const float*)d_in[0];
    const float* Wq = (const float*)d_in[1];
    const float* bq = (const float*)d_in[2];
    const float* Wk = (const float*)d_in[3];
    const float* bk = (const float*)d_in[4];
    const float* Wv = (const float*)d_in[5];
    const float* bv = (const float*)d_in[6];
    const float* Wc = (const float*)d_in[7];
    const float* bc = (const float*)d_in[8];
    float* out = (float*)d_out;

    // workspace (~77 MB): xh 32MB | y 32MB | Wall 8MB | ball | kvg | ksg
    char* W = (char*)d_ws;
    f16* xh   = (f16*)W;
    f16* y_ws = (f16*)(W + 33554432);
    f16* Wall = (f16*)(W + 67108864);
    float* ball = (float*)(W + 75497472);
    float* kvg  = (float*)(W + 75513856);
    float* ksg  = (float*)(W + 76562432);

    prep<<<20480, 256, 0, stream>>>(x, xh, Wq, Wk, Wv, Wc, bq, bk, bv, bc,
                                    Wall, ball, kvg);

    gemm_kv<<<dim3(32, 16), 256, 0, stream>>>(xh, Wall, ball, kvg, ksg);

    gemm_qy<<<dim3(32, 8), 256, 0, stream>>>(xh, Wall, ball, kvg, ksg, y_ws);

    gemm_out<<<dim3(32, 8), 256, 0, stream>>>(y_ws, Wall, ball, out);
}

// Round 16
// 226.770 us; speedup vs baseline: 1.0995x; 1.0995x over previous
//
#include <hip/hip_runtime.h>
#include <math.h>

#define EMBED 1024
#define HEADS 16
#define HD 64
#define BATCH 4
#define TSEQ 4096
#define BH (BATCH * HEADS)
#define MROWS (BATCH * TSEQ)   // 16384

typedef _Float16 f16;
typedef __attribute__((ext_vector_type(4))) _Float16 f16x4;
typedef __attribute__((ext_vector_type(8))) _Float16 f16x8;
typedef __attribute__((ext_vector_type(4))) float f32x4;

#define GLOBAL_AS __attribute__((address_space(1)))
#define LDS_AS __attribute__((address_space(3)))

__device__ __forceinline__ float elu1(float v) {
    return v > 0.f ? v + 1.f : __expf(v);
}

// XOR-swizzled element offset in a [rows][cols] f16 tile; 16B granules.
__device__ __forceinline__ int swzc(int row, int col, int cols) {
    int g = (col >> 3) ^ (row & 7);
    return row * cols + (g << 3) + (col & 7);
}

__device__ __forceinline__ f16x8 fragld(const f16* t, int row, int k, int cols) {
    return *(const f16x8*)&t[swzc(row, k, cols)];
}

__device__ __forceinline__ f32x4 mfma16(f16x8 a, f16x8 b, f32x4 c) {
    return __builtin_amdgcn_mfma_f32_16x16x32_f16(a, b, c, 0, 0, 0);
}

// async global->LDS, 16B per lane. lds dest must be wave-uniform base.
__device__ __forceinline__ void gld_lds16(const f16* g, f16* l) {
    __builtin_amdgcn_global_load_lds((const GLOBAL_AS void*)g, (LDS_AS void*)l, 16, 0, 0);
}

// ---------------------------------------------------------------------------
// prep: blocks [0,16384): x fp32 -> f16.  blocks [16384,20480): pack weights
// f16 + biases + zero kv/ks accumulators.
// ---------------------------------------------------------------------------
__global__ __launch_bounds__(256) void prep(
    const float* __restrict__ x, f16* __restrict__ xh,
    const float* __restrict__ Wq, const float* __restrict__ Wk,
    const float* __restrict__ Wv, const float* __restrict__ Wc,
    const float* __restrict__ bq, const float* __restrict__ bk,
    const float* __restrict__ bv, const float* __restrict__ bc,
    f16* __restrict__ Wall, float* __restrict__ ball, float* __restrict__ kvz)
{
    int bid = blockIdx.x;
    if (bid < 16384) {
        size_t i4 = (size_t)bid * 256 + threadIdx.x;
        float4 f = *(const float4*)&x[i4 * 4];
        f16x4 h = {(f16)f.x, (f16)f.y, (f16)f.z, (f16)f.w};
        *(f16x4*)&xh[i4 * 4] = h;
    } else {
        int i4 = (bid - 16384) * 256 + threadIdx.x;    // < 1048576
        int cls = i4 >> 18;
        const float* W = cls == 0 ? Wq : cls == 1 ? Wk : cls == 2 ? Wv : Wc;
        int off = (i4 & 0x3FFFF) * 4;
        float4 f = *(const float4*)&W[off];
        f16x4 h = {(f16)f.x, (f16)f.y, (f16)f.z, (f16)f.w};
        *(f16x4*)&Wall[(size_t)i4 * 4] = h;
        if (i4 < 4096) {
            int c2 = i4 >> 10;
            const float* bb = c2 == 0 ? bq : c2 == 1 ? bk : c2 == 2 ? bv : bc;
            ball[i4] = bb[i4 & 1023];
        }
        if (i4 < 66560) {   // (64*64*64 + 64*64)/4 floats of kv+ks
            *(float4*)&kvz[i4 * 4] = (float4){0.f, 0.f, 0.f, 0.f};
        }
    }
}

// ---------------------------------------------------------------------------
// gemm_kv: grid (32 m-chunks, 16 heads); each block loops over 4 m-tiles of
// one batch. Per tile: C[128t x 128c] = xh @ [Wk_h;Wv_h]^T,
// k=elu(C[:,0:64]+bk), v=C[:,64:128]+bv -> LDS transposed ->
// kvacc += v^T k (reg, MFMA), ksacc += sum_t k. Single atomic flush per
// block. (r14-verified: 92 us, MfmaUtil 33; 512 blocks = full residency)
// ---------------------------------------------------------------------------
__global__ __launch_bounds__(256) void gemm_kv(
    const f16* __restrict__ xh, const f16* __restrict__ Wall,
    const float* __restrict__ ball,
    float* __restrict__ kvg, float* __restrict__ ksg)
{
    __shared__ __align__(16) f16 smem[2 * 128 * 64];   // As | Bs (32KB)
    f16* As = smem;
    f16* Bs = smem + 128 * 64;

    const int tid = threadIdx.x, lane = tid & 63, w = tid >> 6;
    const int wr = w >> 1, wc4 = w & 1, l15 = lane & 15, l4 = lane >> 4;

    const int h = blockIdx.y;

    const int gcol = ((lane & 7) ^ (lane >> 3)) << 3;
    const int rsub = lane >> 3;

    const int wrow = w * 32 + rsub;       // 0..127
    const int brow_idx = (wrow < 64) ? (1024 + h * 64 + wrow)
                                     : (2048 + h * 64 + (wrow - 64));
    const size_t brow = (size_t)brow_idx * EMBED + gcol;
    const float* biasp = ball + (wc4 ? 2048 : 1024) + h * 64;

    f32x4 kvacc[4];
    #pragma unroll
    for (int j = 0; j < 4; ++j) kvacc[j] = (f32x4){0.f, 0.f, 0.f, 0.f};
    float ksacc = 0.f;

    for (int mi = 0; mi < 4; ++mi) {
        const int m0 = (blockIdx.x * 4 + mi) * 128;
        const size_t arow = (size_t)(m0 + w * 32 + rsub) * EMBED + gcol;

        f32x4 acc[4][4];
        #pragma unroll
        for (int i = 0; i < 4; ++i)
            #pragma unroll
            for (int j = 0; j < 4; ++j) acc[i][j] = (f32x4){0.f, 0.f, 0.f, 0.f};

        for (int k0 = 0; k0 < EMBED; k0 += 64) {
            #pragma unroll
            for (int c = 0; c < 4; ++c) {
                gld_lds16(&xh[arow + (size_t)c * 8 * EMBED + k0], &As[(w * 4 + c) * 512]);
                gld_lds16(&Wall[brow + (size_t)c * 8 * EMBED + k0], &Bs[(w * 4 + c) * 512]);
            }
            __syncthreads();
            #pragma unroll
            for (int kk = 0; kk < 64; kk += 32) {
                f16x8 af[4], bf[4];
                #pragma unroll
                for (int i = 0; i < 4; ++i)
                    af[i] = fragld(As, wr * 64 + i * 16 + l15, kk + l4 * 8, 64);
                #pragma unroll
                for (int j = 0; j < 4; ++j)
                    bf[j] = fragld(Bs, wc4 * 64 + j * 16 + l15, kk + l4 * 8, 64);
                #pragma unroll
                for (int i = 0; i < 4; ++i)
                    #pragma unroll
                    for (int j = 0; j < 4; ++j)
                        acc[i][j] = mfma16(af[i], bf[j], acc[i][j]);
            }
            __syncthreads();
        }

        // kv epilogue: acc -> kt/vt LDS [64 d][128 t] (transposed, swizzled)
        f16* kt = As;
        f16* vt = Bs;
        #pragma unroll
        for (int j = 0; j < 4; ++j) {
            int d = j * 16 + l15;
            float bj = biasp[d];
            f16* dst = wc4 ? vt : kt;
            #pragma unroll
            for (int i = 0; i < 4; ++i) {
                int t0 = wr * 64 + i * 16 + l4 * 4;
                f16x4 hv;
                #pragma unroll
                for (int r = 0; r < 4; ++r) {
                    float vv = acc[i][j][r] + bj;
                    if (!wc4) vv = elu1(vv);
                    hv[r] = (f16)vv;
                }
                *(f16x4*)&dst[swzc(d, t0, 128)] = hv;
            }
        }
        __syncthreads();

        // kvacc[e][d] += sum_t v[t,e] k[t,d]; wave w owns e range [16w,16w+16)
        #pragma unroll
        for (int tc = 0; tc < 4; ++tc) {
            f16x8 a = fragld(vt, 16 * w + l15, tc * 32 + l4 * 8, 128);
            #pragma unroll
            for (int j = 0; j < 4; ++j) {
                f16x8 bfr = fragld(kt, j * 16 + l15, tc * 32 + l4 * 8, 128);
                kvacc[j] = mfma16(a, bfr, kvacc[j]);
            }
        }
        {
            int d = tid & 63, q4 = tid >> 6;
            #pragma unroll
            for (int t8 = 0; t8 < 32; t8 += 8) {
                f16x8 k8 = fragld(kt, d, q4 * 32 + t8, 128);
                #pragma unroll
                for (int e = 0; e < 8; ++e) ksacc += (float)k8[e];
            }
        }
        __syncthreads();   // kt/vt reads done before next chunk re-stages As/Bs
    }

    const int bh = (blockIdx.x >> 3) * HEADS + h;   // 8 m-chunks per batch
    #pragma unroll
    for (int j = 0; j < 4; ++j)
        #pragma unroll
        for (int r = 0; r < 4; ++r)
            atomicAdd(&kvg[(size_t)bh * 4096 +
                           (size_t)(16 * w + l4 * 4 + r) * HD + j * 16 + l15],
                      kvacc[j][r]);
    atomicAdd(&ksg[bh * HD + (tid & 63)], ksacc);
}

// ---------------------------------------------------------------------------
// gemm_qy: grid (64 m-chunks, 8 q-classes) = 512 blocks (full residency);
// block loops 2 m-tiles of one batch (16 chunks/batch). Per tile: q for
// heads 2ny,2ny+1, in-block z + y = (q @ kv)*z, coalesced y store.
// kvs/kss staged once per block.
// ---------------------------------------------------------------------------
__global__ __launch_bounds__(256) void gemm_qy(
    const f16* __restrict__ xh, const f16* __restrict__ Wall,
    const float* __restrict__ ball,
    const float* __restrict__ kvg, const float* __restrict__ ksg,
    f16* __restrict__ y)
{
    __shared__ __align__(16) f16 smem[2 * 128 * 64];   // As|Bs -> qtile -> ytile
    __shared__ __align__(16) f16 kvs[2][64 * 64];      // per-head kv (f16, swz)
    __shared__ float kss[2][64];
    __shared__ float zs[128][2];
    f16* As = smem;
    f16* Bs = smem + 128 * 64;

    const int tid = threadIdx.x, lane = tid & 63, w = tid >> 6;
    const int wr = w >> 1, wc4 = w & 1, l15 = lane & 15, l4 = lane >> 4;

    const int ny = blockIdx.y;            // 0..7
    const int n0 = ny * 128;
    const int batch = blockIdx.x >> 4;    // 16 m-chunks per batch
    const int bh0 = batch * HEADS + 2 * ny;

    const int gcol = ((lane & 7) ^ (lane >> 3)) << 3;
    const int rsub = lane >> 3;
    const size_t brow = (size_t)(n0 + w * 32 + rsub) * EMBED + gcol;

    // stage kv for both heads (fp32 -> f16, swizzled) + ksum — once per block
    #pragma unroll
    for (int c = 0; c < 8; ++c) {
        int idx = tid + c * 256;          // 0..2047
        int hh = idx >> 10;
        int rem = idx & 1023;
        int e = rem >> 4, d4 = (rem & 15) << 2;
        float4 f = *(const float4*)&kvg[(size_t)(bh0 + hh) * 4096 + e * 64 + d4];
        f16x4 hv = {(f16)f.x, (f16)f.y, (f16)f.z, (f16)f.w};
        *(f16x4*)&kvs[hh][swzc(e, d4, 64)] = hv;
    }
    if (tid < 128) kss[tid >> 6][tid & 63] = ksg[(bh0 + (tid >> 6)) * HD + (tid & 63)];

    const int hh = w >> 1;                // y-MFMA wave mapping
    const int eh = (w & 1) * 32;

    for (int mi = 0; mi < 2; ++mi) {
        const int m0 = (blockIdx.x * 2 + mi) * 128;
        const size_t arow = (size_t)(m0 + w * 32 + rsub) * EMBED + gcol;

        f32x4 acc[4][4];
        #pragma unroll
        for (int i = 0; i < 4; ++i)
            #pragma unroll
            for (int j = 0; j < 4; ++j) acc[i][j] = (f32x4){0.f, 0.f, 0.f, 0.f};

        for (int k0 = 0; k0 < EMBED; k0 += 64) {
            #pragma unroll
            for (int c = 0; c < 4; ++c) {
                gld_lds16(&xh[arow + (size_t)c * 8 * EMBED + k0], &As[(w * 4 + c) * 512]);
                gld_lds16(&Wall[brow + (size_t)c * 8 * EMBED + k0], &Bs[(w * 4 + c) * 512]);
            }
            __syncthreads();
            #pragma unroll
            for (int kk = 0; kk < 64; kk += 32) {
                f16x8 af[4], bf[4];
                #pragma unroll
                for (int i = 0; i < 4; ++i)
                    af[i] = fragld(As, wr * 64 + i * 16 + l15, kk + l4 * 8, 64);
                #pragma unroll
                for (int j = 0; j < 4; ++j)
                    bf[j] = fragld(Bs, wc4 * 64 + j * 16 + l15, kk + l4 * 8, 64);
                #pragma unroll
                for (int i = 0; i < 4; ++i)
                    #pragma unroll
                    for (int j = 0; j < 4; ++j)
                        acc[i][j] = mfma16(af[i], bf[j], acc[i][j]);
            }
            __syncthreads();
        }

        // q epilogue -> qtile smem [128 t][128 c] swizzled
        #pragma unroll
        for (int j = 0; j < 4; ++j) {
            int c = wc4 * 64 + j * 16 + l15;
            float bj = ball[n0 + c];
            #pragma unroll
            for (int i = 0; i < 4; ++i) {
                #pragma unroll
                for (int r = 0; r < 4; ++r) {
                    int t = wr * 64 + i * 16 + l4 * 4 + r;
                    smem[swzc(t, c, 128)] = (f16)elu1(acc[i][j][r] + bj);
                }
            }
        }
        __syncthreads();

        // z[t][hh2] = 1/(q[t, hh2-head] . ksum + 1e-6); one thread per (t,hh2)
        {
            int t = tid >> 1, hh2 = tid & 1;
            float s = 0.f;
            #pragma unroll
            for (int d8 = 0; d8 < 64; d8 += 8) {
                f16x8 qv = fragld(smem, t, hh2 * 64 + d8, 128);
                #pragma unroll
                for (int e = 0; e < 8; ++e) s += (float)qv[e] * kss[hh2][d8 + e];
            }
            zs[t][hh2] = 1.f / (s + 1e-6f);
        }

        // y^T[e][t] per head: wave w -> head hh=w>>1, e-half (w&1)*32
        f32x4 yacc[2][8];
        #pragma unroll
        for (int et = 0; et < 2; ++et)
            #pragma unroll
            for (int jn = 0; jn < 8; ++jn) yacc[et][jn] = (f32x4){0.f, 0.f, 0.f, 0.f};
        #pragma unroll
        for (int kk = 0; kk < 64; kk += 32) {
            f16x8 a0 = fragld(kvs[hh], eh + l15, kk + l4 * 8, 64);
            f16x8 a1 = fragld(kvs[hh], eh + 16 + l15, kk + l4 * 8, 64);
            #pragma unroll
            for (int jn = 0; jn < 8; ++jn) {
                f16x8 bq8 = fragld(smem, jn * 16 + l15, hh * 64 + kk + l4 * 8, 128);
                yacc[0][jn] = mfma16(a0, bq8, yacc[0][jn]);
                yacc[1][jn] = mfma16(a1, bq8, yacc[1][jn]);
            }
        }
        __syncthreads();   // qtile reads done; zs visible

        // scale by z, write ytile into smem [128 t][128 c] swizzled
        #pragma unroll
        for (int et = 0; et < 2; ++et) {
            #pragma unroll
            for (int jn = 0; jn < 8; ++jn) {
                int t = jn * 16 + l15;
                float z = zs[t][hh];
                int c0 = hh * 64 + eh + et * 16 + l4 * 4;
                f16x4 hv;
                #pragma unroll
                for (int r = 0; r < 4; ++r) hv[r] = (f16)(yacc[et][jn][r] * z);
                *(f16x4*)&smem[swzc(t, c0, 128)] = hv;
            }
        }
        __syncthreads();

        // coalesced y store
        #pragma unroll
        for (int p = 0; p < 8; ++p) {
            int idx = tid + p * 256;
            int row = idx >> 4, g8 = (idx & 15) << 3;
            f16x8 v = *(const f16x8*)&smem[swzc(row, g8, 128)];
            *(f16x8*)&y[(size_t)(m0 + row) * EMBED + n0 + g8] = v;
        }
        __syncthreads();   // smem reads done before next chunk re-stages As/Bs
    }
}

// ---------------------------------------------------------------------------
// gemm_out: grid (64 m-chunks, 8 n-tiles) = 512 blocks (full residency);
// block loops 2 m-tiles. out = y @ Wc^T + bc, fp32 nontemporal stores.
// ---------------------------------------------------------------------------
__global__ __launch_bounds__(256) void gemm_out(
    const f16* __restrict__ y, const f16* __restrict__ Wall,
    const float* __restrict__ ball, float* __restrict__ out)
{
    __shared__ __align__(16) f16 As[128 * 64];
    __shared__ __align__(16) f16 Bs[128 * 64];

    const int tid = threadIdx.x, lane = tid & 63, w = tid >> 6;
    const int wr = w >> 1, wc4 = w & 1, l15 = lane & 15, l4 = lane >> 4;
    const int n0 = blockIdx.y * 128;

    const int gcol = ((lane & 7) ^ (lane >> 3)) << 3;
    const int rsub = lane >> 3;
    const size_t brow = (size_t)(3072 + n0 + w * 32 + rsub) * EMBED + gcol;

    for (int mi = 0; mi < 2; ++mi) {
        const int m0 = (blockIdx.x * 2 + mi) * 128;
        const size_t arow = (size_t)(m0 + w * 32 + rsub) * EMBED + gcol;

        f32x4 acc[4][4];
        #pragma unroll
        for (int i = 0; i < 4; ++i)
            #pragma unroll
            for (int j = 0; j < 4; ++j) acc[i][j] = (f32x4){0.f, 0.f, 0.f, 0.f};

        for (int k0 = 0; k0 < EMBED; k0 += 64) {
            #pragma unroll
            for (int c = 0; c < 4; ++c) {
                gld_lds16(&y[arow + (size_t)c * 8 * EMBED + k0], &As[(w * 4 + c) * 512]);
                gld_lds16(&Wall[brow + (size_t)c * 8 * EMBED + k0], &Bs[(w * 4 + c) * 512]);
            }
            __syncthreads();
            #pragma unroll
            for (int kk = 0; kk < 64; kk += 32) {
                f16x8 af[4], bf[4];
                #pragma unroll
                for (int i = 0; i < 4; ++i)
                    af[i] = fragld(As, wr * 64 + i * 16 + l15, kk + l4 * 8, 64);
                #pragma unroll
                for (int j = 0; j < 4; ++j)
                    bf[j] = fragld(Bs, wc4 * 64 + j * 16 + l15, kk + l4 * 8, 64);
                #pragma unroll
                for (int i = 0; i < 4; ++i)
                    #pragma unroll
                    for (int j = 0; j < 4; ++j)
                        acc[i][j] = mfma16(af[i], bf[j], acc[i][j]);
            }
            __syncthreads();
        }

        #pragma unroll
        for (int j = 0; j < 4; ++j) {
            int n = n0 + wc4 * 64 + j * 16 + l15;
            float bj = ball[3072 + n];
            #pragma unroll
            for (int i = 0; i < 4; ++i) {
                #pragma unroll
                for (int r = 0; r < 4; ++r) {
                    int m = m0 + wr * 64 + i * 16 + l4 * 4 + r;
                    __builtin_nontemporal_store(acc[i][j][r] + bj,
                                                &out[(size_t)m * EMBED + n]);
                }
            }
        }
    }
}

// ---------------------------------------------------------------------------
extern "C" void kernel_launch(void* const* d_in, const int* in_sizes, int n_in,
                              void* d_out, int out_size, void* d_ws, size_t ws_size,
                              hipStream_t stream) {
    (void)in_sizes; (void)n_in; (void)out_size; (void)ws_size;
    const float* x  = (const float*)d_in[0];
    const float* Wq = (const float*)d_in[1];
    const float* bq = (const float*)d_in[2];
    const float* Wk = (const float*)d_in[3];
    const float* bk = (const float*)d_in[4];
    const float* Wv = (const float*)d_in[5];
    const float* bv = (const float*)d_in[6];
    const float* Wc = (const float*)d_in[7];
    const float* bc = (const float*)d_in[8];
    float* out = (float*)d_out;

    // workspace (~77 MB): xh 32MB | y 32MB | Wall 8MB | ball | kvg | ksg
    char* W = (char*)d_ws;
    f16* xh   = (f16*)W;
    f16* y_ws = (f16*)(W + 33554432);
    f16* Wall = (f16*)(W + 67108864);
    float* ball = (float*)(W + 75497472);
    float* kvg  = (float*)(W + 75513856);
    float* ksg  = (float*)(W + 76562432);

    prep<<<20480, 256, 0, stream>>>(x, xh, Wq, Wk, Wv, Wc, bq, bk, bv, bc,
                                    Wall, ball, kvg);

    gemm_kv<<<dim3(32, 16), 256, 0, stream>>>(xh, Wall, ball, kvg, ksg);

    gemm_qy<<<dim3(64, 8), 256, 0, stream>>>(xh, Wall, ball, kvg, ksg, y_ws);

    gemm_out<<<dim3(64, 8), 256, 0, stream>>>(y_ws, Wall, ball, out);
}

// Round 17
// 201.160 us; speedup vs baseline: 1.2394x; 1.1273x over previous
//
#include <hip/hip_runtime.h>
#include <math.h>

#define EMBED 1024
#define HEADS 16
#define HD 64
#define BATCH 4
#define TSEQ 4096
#define BH (BATCH * HEADS)
#define MROWS (BATCH * TSEQ)   // 16384

typedef _Float16 f16;
typedef __attribute__((ext_vector_type(4))) _Float16 f16x4;
typedef __attribute__((ext_vector_type(8))) _Float16 f16x8;
typedef __attribute__((ext_vector_type(4))) float f32x4;

#define GLOBAL_AS __attribute__((address_space(1)))
#define LDS_AS __attribute__((address_space(3)))

__device__ __forceinline__ float elu1(float v) {
    return v > 0.f ? v + 1.f : __expf(v);
}

// XOR-swizzled element offset in a [rows][cols] f16 tile; 16B granules.
__device__ __forceinline__ int swzc(int row, int col, int cols) {
    int g = (col >> 3) ^ (row & 7);
    return row * cols + (g << 3) + (col & 7);
}

__device__ __forceinline__ f16x8 fragld(const f16* t, int row, int k, int cols) {
    return *(const f16x8*)&t[swzc(row, k, cols)];
}

__device__ __forceinline__ f32x4 mfma16(f16x8 a, f16x8 b, f32x4 c) {
    return __builtin_amdgcn_mfma_f32_16x16x32_f16(a, b, c, 0, 0, 0);
}

// async global->LDS, 16B per lane. lds dest must be wave-uniform base.
__device__ __forceinline__ void gld_lds16(const f16* g, f16* l) {
    __builtin_amdgcn_global_load_lds((const GLOBAL_AS void*)g, (LDS_AS void*)l, 16, 0, 0);
}

// ---------------------------------------------------------------------------
// prep: blocks [0,16384): x fp32 -> f16.  blocks [16384,20480): pack weights
// f16 + biases + zero kv/ks accumulators.
// ---------------------------------------------------------------------------
__global__ __launch_bounds__(256) void prep(
    const float* __restrict__ x, f16* __restrict__ xh,
    const float* __restrict__ Wq, const float* __restrict__ Wk,
    const float* __restrict__ Wv, const float* __restrict__ Wc,
    const float* __restrict__ bq, const float* __restrict__ bk,
    const float* __restrict__ bv, const float* __restrict__ bc,
    f16* __restrict__ Wall, float* __restrict__ ball, float* __restrict__ kvz)
{
    int bid = blockIdx.x;
    if (bid < 16384) {
        size_t i4 = (size_t)bid * 256 + threadIdx.x;
        float4 f = *(const float4*)&x[i4 * 4];
        f16x4 h = {(f16)f.x, (f16)f.y, (f16)f.z, (f16)f.w};
        *(f16x4*)&xh[i4 * 4] = h;
    } else {
        int i4 = (bid - 16384) * 256 + threadIdx.x;    // < 1048576
        int cls = i4 >> 18;
        const float* W = cls == 0 ? Wq : cls == 1 ? Wk : cls == 2 ? Wv : Wc;
        int off = (i4 & 0x3FFFF) * 4;
        float4 f = *(const float4*)&W[off];
        f16x4 h = {(f16)f.x, (f16)f.y, (f16)f.z, (f16)f.w};
        *(f16x4*)&Wall[(size_t)i4 * 4] = h;
        if (i4 < 4096) {
            int c2 = i4 >> 10;
            const float* bb = c2 == 0 ? bq : c2 == 1 ? bk : c2 == 2 ? bv : bc;
            ball[i4] = bb[i4 & 1023];
        }
        if (i4 < 66560) {   // (64*64*64 + 64*64)/4 floats of kv+ks
            *(float4*)&kvz[i4 * 4] = (float4){0.f, 0.f, 0.f, 0.f};
        }
    }
}

// ---------------------------------------------------------------------------
// gemm_kv: grid (32 m-chunks, 16 heads); each block loops over 4 m-tiles of
// one batch. Per tile: C[128t x 128c] = xh @ [Wk_h;Wv_h]^T,
// k=elu(C[:,0:64]+bk), v=C[:,64:128]+bv -> LDS transposed ->
// kvacc += v^T k (reg, MFMA), ksacc += sum_t k. Single atomic flush per
// block (4x fewer atomics; 512 blocks = full residency).
// (r14-verified: 92 us, MfmaUtil 33)
// ---------------------------------------------------------------------------
__global__ __launch_bounds__(256) void gemm_kv(
    const f16* __restrict__ xh, const f16* __restrict__ Wall,
    const float* __restrict__ ball,
    float* __restrict__ kvg, float* __restrict__ ksg)
{
    __shared__ __align__(16) f16 smem[2 * 128 * 64];   // As | Bs (32KB)
    f16* As = smem;
    f16* Bs = smem + 128 * 64;

    const int tid = threadIdx.x, lane = tid & 63, w = tid >> 6;
    const int wr = w >> 1, wc4 = w & 1, l15 = lane & 15, l4 = lane >> 4;

    const int h = blockIdx.y;

    const int gcol = ((lane & 7) ^ (lane >> 3)) << 3;
    const int rsub = lane >> 3;

    const int wrow = w * 32 + rsub;       // 0..127
    const int brow_idx = (wrow < 64) ? (1024 + h * 64 + wrow)
                                     : (2048 + h * 64 + (wrow - 64));
    const size_t brow = (size_t)brow_idx * EMBED + gcol;
    const float* biasp = ball + (wc4 ? 2048 : 1024) + h * 64;

    f32x4 kvacc[4];
    #pragma unroll
    for (int j = 0; j < 4; ++j) kvacc[j] = (f32x4){0.f, 0.f, 0.f, 0.f};
    float ksacc = 0.f;

    for (int mi = 0; mi < 4; ++mi) {
        const int m0 = (blockIdx.x * 4 + mi) * 128;
        const size_t arow = (size_t)(m0 + w * 32 + rsub) * EMBED + gcol;

        f32x4 acc[4][4];
        #pragma unroll
        for (int i = 0; i < 4; ++i)
            #pragma unroll
            for (int j = 0; j < 4; ++j) acc[i][j] = (f32x4){0.f, 0.f, 0.f, 0.f};

        for (int k0 = 0; k0 < EMBED; k0 += 64) {
            #pragma unroll
            for (int c = 0; c < 4; ++c) {
                gld_lds16(&xh[arow + (size_t)c * 8 * EMBED + k0], &As[(w * 4 + c) * 512]);
                gld_lds16(&Wall[brow + (size_t)c * 8 * EMBED + k0], &Bs[(w * 4 + c) * 512]);
            }
            __syncthreads();
            #pragma unroll
            for (int kk = 0; kk < 64; kk += 32) {
                f16x8 af[4], bf[4];
                #pragma unroll
                for (int i = 0; i < 4; ++i)
                    af[i] = fragld(As, wr * 64 + i * 16 + l15, kk + l4 * 8, 64);
                #pragma unroll
                for (int j = 0; j < 4; ++j)
                    bf[j] = fragld(Bs, wc4 * 64 + j * 16 + l15, kk + l4 * 8, 64);
                #pragma unroll
                for (int i = 0; i < 4; ++i)
                    #pragma unroll
                    for (int j = 0; j < 4; ++j)
                        acc[i][j] = mfma16(af[i], bf[j], acc[i][j]);
            }
            __syncthreads();
        }

        // kv epilogue: acc -> kt/vt LDS [64 d][128 t] (transposed, swizzled)
        f16* kt = As;
        f16* vt = Bs;
        #pragma unroll
        for (int j = 0; j < 4; ++j) {
            int d = j * 16 + l15;
            float bj = biasp[d];
            f16* dst = wc4 ? vt : kt;
            #pragma unroll
            for (int i = 0; i < 4; ++i) {
                int t0 = wr * 64 + i * 16 + l4 * 4;
                f16x4 hv;
                #pragma unroll
                for (int r = 0; r < 4; ++r) {
                    float vv = acc[i][j][r] + bj;
                    if (!wc4) vv = elu1(vv);
                    hv[r] = (f16)vv;
                }
                *(f16x4*)&dst[swzc(d, t0, 128)] = hv;
            }
        }
        __syncthreads();

        // kvacc[e][d] += sum_t v[t,e] k[t,d]; wave w owns e range [16w,16w+16)
        #pragma unroll
        for (int tc = 0; tc < 4; ++tc) {
            f16x8 a = fragld(vt, 16 * w + l15, tc * 32 + l4 * 8, 128);
            #pragma unroll
            for (int j = 0; j < 4; ++j) {
                f16x8 bfr = fragld(kt, j * 16 + l15, tc * 32 + l4 * 8, 128);
                kvacc[j] = mfma16(a, bfr, kvacc[j]);
            }
        }
        {
            int d = tid & 63, q4 = tid >> 6;
            #pragma unroll
            for (int t8 = 0; t8 < 32; t8 += 8) {
                f16x8 k8 = fragld(kt, d, q4 * 32 + t8, 128);
                #pragma unroll
                for (int e = 0; e < 8; ++e) ksacc += (float)k8[e];
            }
        }
        __syncthreads();   // kt/vt reads done before next chunk re-stages As/Bs
    }

    const int bh = (blockIdx.x >> 3) * HEADS + h;   // 8 m-chunks per batch
    #pragma unroll
    for (int j = 0; j < 4; ++j)
        #pragma unroll
        for (int r = 0; r < 4; ++r)
            atomicAdd(&kvg[(size_t)bh * 4096 +
                           (size_t)(16 * w + l4 * 4 + r) * HD + j * 16 + l15],
                      kvacc[j][r]);
    atomicAdd(&ksg[bh * HD + (tid & 63)], ksacc);
}

// ---------------------------------------------------------------------------
// gemm_qy: grid (128 m-tiles, 8 q-classes). Block computes q for heads
// 2ny, 2ny+1 (cols [ny*128, +128)), then IN-BLOCK: z = 1/(q.ksum+1e-6),
// y = (q @ kv_h) * z, writes y coalesced. Per-wave y mapping: head hh=w>>1,
// e-half (w&1)*32, 8 t-tiles. (r14-verified)
// ---------------------------------------------------------------------------
__global__ __launch_bounds__(256) void gemm_qy(
    const f16* __restrict__ xh, const f16* __restrict__ Wall,
    const float* __restrict__ ball,
    const float* __restrict__ kvg, const float* __restrict__ ksg,
    f16* __restrict__ y)
{
    __shared__ __align__(16) f16 smem[2 * 128 * 64];   // As|Bs -> qtile -> ytile
    __shared__ __align__(16) f16 kvs[2][64 * 64];      // per-head kv (f16, swz)
    __shared__ float kss[2][64];
    __shared__ float zs[128][2];
    f16* As = smem;
    f16* Bs = smem + 128 * 64;

    const int tid = threadIdx.x, lane = tid & 63, w = tid >> 6;
    const int wr = w >> 1, wc4 = w & 1, l15 = lane & 15, l4 = lane >> 4;

    const int m0 = blockIdx.x * 128;
    const int ny = blockIdx.y;            // 0..7
    const int n0 = ny * 128;
    const int bh0 = (m0 >> 12) * HEADS + 2 * ny;

    const int gcol = ((lane & 7) ^ (lane >> 3)) << 3;
    const int rsub = lane >> 3;
    const size_t arow = (size_t)(m0 + w * 32 + rsub) * EMBED + gcol;
    const size_t brow = (size_t)(n0 + w * 32 + rsub) * EMBED + gcol;

    f32x4 acc[4][4];
    #pragma unroll
    for (int i = 0; i < 4; ++i)
        #pragma unroll
        for (int j = 0; j < 4; ++j) acc[i][j] = (f32x4){0.f, 0.f, 0.f, 0.f};

    for (int k0 = 0; k0 < EMBED; k0 += 64) {
        #pragma unroll
        for (int c = 0; c < 4; ++c) {
            gld_lds16(&xh[arow + (size_t)c * 8 * EMBED + k0], &As[(w * 4 + c) * 512]);
            gld_lds16(&Wall[brow + (size_t)c * 8 * EMBED + k0], &Bs[(w * 4 + c) * 512]);
        }
        __syncthreads();
        #pragma unroll
        for (int kk = 0; kk < 64; kk += 32) {
            f16x8 af[4], bf[4];
            #pragma unroll
            for (int i = 0; i < 4; ++i)
                af[i] = fragld(As, wr * 64 + i * 16 + l15, kk + l4 * 8, 64);
            #pragma unroll
            for (int j = 0; j < 4; ++j)
                bf[j] = fragld(Bs, wc4 * 64 + j * 16 + l15, kk + l4 * 8, 64);
            #pragma unroll
            for (int i = 0; i < 4; ++i)
                #pragma unroll
                for (int j = 0; j < 4; ++j)
                    acc[i][j] = mfma16(af[i], bf[j], acc[i][j]);
        }
        __syncthreads();
    }

    // stage kv for both heads (fp32 -> f16, swizzled) + ksum
    #pragma unroll
    for (int c = 0; c < 8; ++c) {
        int idx = tid + c * 256;          // 0..2047
        int hh = idx >> 10;
        int rem = idx & 1023;
        int e = rem >> 4, d4 = (rem & 15) << 2;
        float4 f = *(const float4*)&kvg[(size_t)(bh0 + hh) * 4096 + e * 64 + d4];
        f16x4 hv = {(f16)f.x, (f16)f.y, (f16)f.z, (f16)f.w};
        *(f16x4*)&kvs[hh][swzc(e, d4, 64)] = hv;
    }
    if (tid < 128) kss[tid >> 6][tid & 63] = ksg[(bh0 + (tid >> 6)) * HD + (tid & 63)];

    // q epilogue -> qtile smem [128 t][128 c] swizzled
    #pragma unroll
    for (int j = 0; j < 4; ++j) {
        int c = wc4 * 64 + j * 16 + l15;
        float bj = ball[n0 + c];
        #pragma unroll
        for (int i = 0; i < 4; ++i) {
            #pragma unroll
            for (int r = 0; r < 4; ++r) {
                int t = wr * 64 + i * 16 + l4 * 4 + r;
                smem[swzc(t, c, 128)] = (f16)elu1(acc[i][j][r] + bj);
            }
        }
    }
    __syncthreads();

    // z[t][hh] = 1/(q[t, hh-head] . ksum + 1e-6); one thread per (t,hh)
    {
        int t = tid >> 1, hh = tid & 1;
        float s = 0.f;
        #pragma unroll
        for (int d8 = 0; d8 < 64; d8 += 8) {
            f16x8 qv = fragld(smem, t, hh * 64 + d8, 128);
            #pragma unroll
            for (int e = 0; e < 8; ++e) s += (float)qv[e] * kss[hh][d8 + e];
        }
        zs[t][hh] = 1.f / (s + 1e-6f);
    }

    // y^T[e][t] per head: wave w -> head hh=w>>1, e-half (w&1)*32
    const int hh = w >> 1;
    const int eh = (w & 1) * 32;
    f32x4 yacc[2][8];
    #pragma unroll
    for (int et = 0; et < 2; ++et)
        #pragma unroll
        for (int jn = 0; jn < 8; ++jn) yacc[et][jn] = (f32x4){0.f, 0.f, 0.f, 0.f};
    #pragma unroll
    for (int kk = 0; kk < 64; kk += 32) {
        f16x8 a0 = fragld(kvs[hh], eh + l15, kk + l4 * 8, 64);
        f16x8 a1 = fragld(kvs[hh], eh + 16 + l15, kk + l4 * 8, 64);
        #pragma unroll
        for (int jn = 0; jn < 8; ++jn) {
            f16x8 bq8 = fragld(smem, jn * 16 + l15, hh * 64 + kk + l4 * 8, 128);
            yacc[0][jn] = mfma16(a0, bq8, yacc[0][jn]);
            yacc[1][jn] = mfma16(a1, bq8, yacc[1][jn]);
        }
    }
    __syncthreads();   // qtile reads done; zs visible

    // scale by z, write ytile into smem [128 t][128 c] swizzled
    #pragma unroll
    for (int et = 0; et < 2; ++et) {
        #pragma unroll
        for (int jn = 0; jn < 8; ++jn) {
            int t = jn * 16 + l15;
            float z = zs[t][hh];
            int c0 = hh * 64 + eh + et * 16 + l4 * 4;
            f16x4 hv;
            #pragma unroll
            for (int r = 0; r < 4; ++r) hv[r] = (f16)(yacc[et][jn][r] * z);
            *(f16x4*)&smem[swzc(t, c0, 128)] = hv;
        }
    }
    __syncthreads();

    // coalesced y store
    #pragma unroll
    for (int p = 0; p < 8; ++p) {
        int idx = tid + p * 256;
        int row = idx >> 4, g8 = (idx & 15) << 3;
        f16x8 v = *(const f16x8*)&smem[swzc(row, g8, 128)];
        *(f16x8*)&y[(size_t)(m0 + row) * EMBED + n0 + g8] = v;
    }
}

// ---------------------------------------------------------------------------
// gemm_out: out[M,1024] = y @ Wc^T + bc (Wc = Wall rows 3072..4095), fp32 out.
// Nontemporal stores: out is written once, never re-read this launch.
// (r14-verified)
// ---------------------------------------------------------------------------
__global__ __launch_bounds__(256) void gemm_out(
    const f16* __restrict__ y, const f16* __restrict__ Wall,
    const float* __restrict__ ball, float* __restrict__ out)
{
    __shared__ __align__(16) f16 As[128 * 64];
    __shared__ __align__(16) f16 Bs[128 * 64];

    const int tid = threadIdx.x, lane = tid & 63, w = tid >> 6;
    const int wr = w >> 1, wc4 = w & 1, l15 = lane & 15, l4 = lane >> 4;
    const int m0 = blockIdx.x * 128;
    const int n0 = blockIdx.y * 128;

    const int gcol = ((lane & 7) ^ (lane >> 3)) << 3;
    const int rsub = lane >> 3;
    const size_t arow = (size_t)(m0 + w * 32 + rsub) * EMBED + gcol;
    const size_t brow = (size_t)(3072 + n0 + w * 32 + rsub) * EMBED + gcol;

    f32x4 acc[4][4];
    #pragma unroll
    for (int i = 0; i < 4; ++i)
        #pragma unroll
        for (int j = 0; j < 4; ++j) acc[i][j] = (f32x4){0.f, 0.f, 0.f, 0.f};

    for (int k0 = 0; k0 < EMBED; k0 += 64) {
        #pragma unroll
        for (int c = 0; c < 4; ++c) {
            gld_lds16(&y[arow + (size_t)c * 8 * EMBED + k0], &As[(w * 4 + c) * 512]);
            gld_lds16(&Wall[brow + (size_t)c * 8 * EMBED + k0], &Bs[(w * 4 + c) * 512]);
        }
        __syncthreads();
        #pragma unroll
        for (int kk = 0; kk < 64; kk += 32) {
            f16x8 af[4], bf[4];
            #pragma unroll
            for (int i = 0; i < 4; ++i)
                af[i] = fragld(As, wr * 64 + i * 16 + l15, kk + l4 * 8, 64);
            #pragma unroll
            for (int j = 0; j < 4; ++j)
                bf[j] = fragld(Bs, wc4 * 64 + j * 16 + l15, kk + l4 * 8, 64);
            #pragma unroll
            for (int i = 0; i < 4; ++i)
                #pragma unroll
                for (int j = 0; j < 4; ++j)
                    acc[i][j] = mfma16(af[i], bf[j], acc[i][j]);
        }
        __syncthreads();
    }

    #pragma unroll
    for (int j = 0; j < 4; ++j) {
        int n = n0 + wc4 * 64 + j * 16 + l15;
        float bj = ball[3072 + n];
        #pragma unroll
        for (int i = 0; i < 4; ++i) {
            #pragma unroll
            for (int r = 0; r < 4; ++r) {
                int m = m0 + wr * 64 + i * 16 + l4 * 4 + r;
                __builtin_nontemporal_store(acc[i][j][r] + bj,
                                            &out[(size_t)m * EMBED + n]);
            }
        }
    }
}

// ---------------------------------------------------------------------------
extern "C" void kernel_launch(void* const* d_in, const int* in_sizes, int n_in,
                              void* d_out, int out_size, void* d_ws, size_t ws_size,
                              hipStream_t stream) {
    (void)in_sizes; (void)n_in; (void)out_size; (void)ws_size;
    const float* x  = (const float*)d_in[0];
    const float* Wq = (const float*)d_in[1];
    const float* bq = (const float*)d_in[2];
    const float* Wk = (const float*)d_in[3];
    const float* bk = (const float*)d_in[4];
    const float* Wv = (const float*)d_in[5];
    const float* bv = (const float*)d_in[6];
    const float* Wc = (const float*)d_in[7];
    const float* bc = (const float*)d_in[8];
    float* out = (float*)d_out;

    // workspace (~77 MB): xh 32MB | y 32MB | Wall 8MB | ball | kvg | ksg
    char* W = (char*)d_ws;
    f16* xh   = (f16*)W;
    f16* y_ws = (f16*)(W + 33554432);
    f16* Wall = (f16*)(W + 67108864);
    float* ball = (float*)(W + 75497472);
    float* kvg  = (float*)(W + 75513856);
    float* ksg  = (float*)(W + 76562432);

    prep<<<20480, 256, 0, stream>>>(x, xh, Wq, Wk, Wv, Wc, bq, bk, bv, bc,
                                    Wall, ball, kvg);

    gemm_kv<<<dim3(32, 16), 256, 0, stream>>>(xh, Wall, ball, kvg, ksg);

    gemm_qy<<<dim3(128, 8), 256, 0, stream>>>(xh, Wall, ball, kvg, ksg, y_ws);

    gemm_out<<<dim3(128, 8), 256, 0, stream>>>(y_ws, Wall, ball, out);
}